// Round 1
// baseline (88750.885 us; speedup 1.0000x reference)
//
#include <hip/hip_runtime.h>
#include <math.h>

#define BB 64
#define TT 512
#define FF 512
#define DIN 1024
#define HH 1024
#define G4 4096
#define DOUT 128

// ---------------------------------------------------------------------------
// Kernel 1: Xin[t][b][j] = tanh(x[b][t][:] @ Wi[:,j] + bi[j])
// grid (DIN/256, BT/16), block 256. LDS-stage 16 rows of x (32KB).
// ---------------------------------------------------------------------------
__global__ __launch_bounds__(256) void k_dense_in(
    const float* __restrict__ x, const float* __restrict__ Wi,
    const float* __restrict__ bi, float* __restrict__ Xin)
{
    __shared__ float xs[16][FF];   // 32 KB
    const int jb  = blockIdx.x;    // 0..3
    const int rb  = blockIdx.y;    // 0..2047
    const int tid = threadIdx.x;

    // stage 16 consecutive bt-rows (g = b*T + t), coalesced float4
    const float4* xsrc = (const float4*)(x + (size_t)rb * 16 * FF);
    float4* xdst = (float4*)(&xs[0][0]);
    #pragma unroll
    for (int i = 0; i < 8; ++i) xdst[tid + i * 256] = xsrc[tid + i * 256];
    __syncthreads();

    const int j = jb * 256 + tid;
    float acc[16];
    #pragma unroll
    for (int r = 0; r < 16; ++r) acc[r] = 0.f;

    for (int k = 0; k < FF; ++k) {
        float w = Wi[(size_t)k * DIN + j];   // coalesced across lanes
        #pragma unroll
        for (int r = 0; r < 16; ++r) acc[r] += xs[r][k] * w;  // LDS broadcast
    }
    const float bbv = bi[j];
    #pragma unroll
    for (int r = 0; r < 16; ++r) {
        int g = rb * 16 + r;
        int b = g >> 9;        // g / T
        int t = g & 511;       // g % T
        Xin[((size_t)t * BB + b) * DIN + j] = tanhf(acc[r] + bbv);
    }
}

// ---------------------------------------------------------------------------
// Kernel 2: one LSTM cell step for one layer.
// z[b][col] = A1[b,:]@M1[:,col] + A2[b,:]@M2[:,col] + bias[col], col = g*H + j
// then gate math -> h_out, c (in place).
// grid 256 blocks: block owns j in [j0, j0+4) for ALL 4 gates x all 64 b.
// block 256 threads = (ks 8) x (bgrp 8) x (g 4). K=2048 in 32 chunks of 64,
// A-chunk staged in LDS [64][68]; thread k-subrange = 8 per chunk.
// Thread accumulates 8 b (b = bgrp + 8*bi) x 4 j. 8-way k-split reduced in LDS,
// gate epilogue fused (1 output per thread).
// ---------------------------------------------------------------------------
__global__ __launch_bounds__(256) void k_step(
    const float* __restrict__ A1, const float* __restrict__ M1,
    const float* __restrict__ A2, const float* __restrict__ M2,
    const float* __restrict__ bias,
    float* __restrict__ c, float* __restrict__ h_out)
{
    __shared__ float as[64][68];          // 17.4 KB (stride 68: conflict-free b128)
    __shared__ float zb[8][4][4][64];     // 32 KB  [ks][g][jj][b]

    const int tid  = threadIdx.x;
    const int ks   = tid >> 5;          // 0..7  k-split
    const int bgrp = (tid >> 2) & 7;    // 0..7
    const int g    = tid & 3;           // 0..3  gate
    const int j0   = blockIdx.x * 4;

    float acc[8][4];
    #pragma unroll
    for (int bi = 0; bi < 8; ++bi)
        #pragma unroll
        for (int jj = 0; jj < 4; ++jj) acc[bi][jj] = 0.f;

    for (int ch = 0; ch < 32; ++ch) {
        const float* Arow = (ch < 16) ? A1 : A2;
        const float* M    = (ch < 16) ? M1 : M2;
        const int koff    = (ch < 16) ? ch * 64 : (ch - 16) * 64;

        __syncthreads();
        // stage A chunk: 64 rows x 64 floats, coalesced float4
        {
            const int fb = tid >> 2;       // row 0..63
            const int q0 = tid & 3;
            const float4* src = (const float4*)(Arow + (size_t)fb * DIN + koff);
            #pragma unroll
            for (int l = 0; l < 4; ++l) {
                float4 v = src[q0 + l * 4];
                int kk = (q0 + l * 4) * 4;
                as[fb][kk + 0] = v.x; as[fb][kk + 1] = v.y;
                as[fb][kk + 2] = v.z; as[fb][kk + 3] = v.w;
            }
        }
        __syncthreads();

        // compute on k in [ks*8, ks*8+8)
        #pragma unroll
        for (int kb = 0; kb < 2; ++kb) {
            const int k = ks * 8 + kb * 4;
            float4 w[4];
            #pragma unroll
            for (int kk = 0; kk < 4; ++kk)
                w[kk] = *(const float4*)(M + (size_t)(koff + k + kk) * G4 + g * HH + j0);
            #pragma unroll
            for (int bi = 0; bi < 8; ++bi) {
                const int b = bgrp + bi * 8;
                float4 a = *(const float4*)(&as[b][k]);
                acc[bi][0] += a.x * w[0].x + a.y * w[1].x + a.z * w[2].x + a.w * w[3].x;
                acc[bi][1] += a.x * w[0].y + a.y * w[1].y + a.z * w[2].y + a.w * w[3].y;
                acc[bi][2] += a.x * w[0].z + a.y * w[1].z + a.z * w[2].z + a.w * w[3].z;
                acc[bi][3] += a.x * w[0].w + a.y * w[1].w + a.z * w[2].w + a.w * w[3].w;
            }
        }
    }

    __syncthreads();
    #pragma unroll
    for (int bi = 0; bi < 8; ++bi) {
        const int b = bgrp + bi * 8;
        #pragma unroll
        for (int jj = 0; jj < 4; ++jj) zb[ks][g][jj][b] = acc[bi][jj];
    }
    __syncthreads();

    // epilogue: one (b, jj) per thread
    {
        const int b = tid >> 2, jj = tid & 3;
        float z[4];
        #pragma unroll
        for (int gg = 0; gg < 4; ++gg) {
            float s = 0.f;
            #pragma unroll
            for (int kk = 0; kk < 8; ++kk) s += zb[kk][gg][jj][b];
            z[gg] = s + bias[gg * HH + j0 + jj];
        }
        const float ig = 1.f / (1.f + expf(-z[0]));
        const float fg = 1.f / (1.f + expf(-z[1]));
        const float cc = tanhf(z[2]);
        const float og = 1.f / (1.f + expf(-z[3]));
        const int idx = b * HH + j0 + jj;
        const float cn = fg * c[idx] + ig * cc;
        c[idx] = cn;
        h_out[idx] = og * tanhf(cn);
    }
}

// ---------------------------------------------------------------------------
// Kernel 3: out[b][o] = tanh(h1[b,:] @ Wo[:,o] + bo[o])
// ---------------------------------------------------------------------------
__global__ __launch_bounds__(128) void k_out(
    const float* __restrict__ h1, const float* __restrict__ Wo,
    const float* __restrict__ bo, float* __restrict__ out)
{
    __shared__ float hs[HH];
    const int b = blockIdx.x;
    for (int i = threadIdx.x; i < HH; i += 128) hs[i] = h1[b * HH + i];
    __syncthreads();
    const int o = threadIdx.x;
    float acc = 0.f;
    for (int k = 0; k < HH; ++k) acc += hs[k] * Wo[k * DOUT + o];
    out[b * DOUT + o] = tanhf(acc + bo[o]);
}

// ---------------------------------------------------------------------------
extern "C" void kernel_launch(void* const* d_in, const int* in_sizes, int n_in,
                              void* d_out, int out_size, void* d_ws, size_t ws_size,
                              hipStream_t stream)
{
    const float* x  = (const float*)d_in[0];
    const float* Wi = (const float*)d_in[1];
    const float* bi = (const float*)d_in[2];
    const float* W0 = (const float*)d_in[3];
    const float* U0 = (const float*)d_in[4];
    const float* b0 = (const float*)d_in[5];
    const float* W1 = (const float*)d_in[6];
    const float* U1 = (const float*)d_in[7];
    const float* b1 = (const float*)d_in[8];
    const float* Wo = (const float*)d_in[9];
    const float* bo = (const float*)d_in[10];
    float* out = (float*)d_out;

    char* ws = (char*)d_ws;
    float* Xin = (float*)ws;                                   // [T][B][DIN] 134 MB
    size_t off = (size_t)TT * BB * DIN * sizeof(float);
    float* states = (float*)(ws + off);                        // 6 x [64][1024]
    float* h0a = states + 0 * BB * HH;
    float* h0b = states + 1 * BB * HH;
    float* h1a = states + 2 * BB * HH;
    float* h1b = states + 3 * BB * HH;
    float* c0  = states + 4 * BB * HH;
    float* c1  = states + 5 * BB * HH;

    // zero initial h/c (ws is poisoned 0xAA before every timed call)
    hipMemsetAsync(states, 0, (size_t)6 * BB * HH * sizeof(float), stream);

    k_dense_in<<<dim3(DIN / 256, (BB * TT) / 16), 256, 0, stream>>>(x, Wi, bi, Xin);

    const float* h0r = h0a; float* h0w = h0b;
    const float* h1r = h1a; float* h1w = h1b;
    for (int t = 0; t < TT; ++t) {
        k_step<<<256, 256, 0, stream>>>(Xin + (size_t)t * BB * DIN, W0, h0r, U0, b0, c0, h0w);
        k_step<<<256, 256, 0, stream>>>(h0w, W1, h1r, U1, b1, c1, h1w);
        const float* tmp;
        tmp = h0r; h0r = h0w; h0w = (float*)tmp;
        tmp = h1r; h1r = h1w; h1w = (float*)tmp;
    }
    k_out<<<BB, 128, 0, stream>>>(h1r, Wo, bo, out);
}

// Round 2
// 11044.559 us; speedup vs baseline: 8.0357x; 8.0357x over previous
//
#include <hip/hip_runtime.h>
#include <math.h>

#define BB 64
#define TT 512
#define FF 512
#define DIN 1024
#define HH 1024
#define G4 4096
#define DOUT 128

typedef _Float16 f16;
typedef _Float16 f16x8 __attribute__((ext_vector_type(8)));
typedef float f32x4 __attribute__((ext_vector_type(4)));

// A-fragment-linear layout for a [64 x 1024] fp16 activation matrix:
//   element (m=row 0..63, k=col 0..1023) lives at
//   ((k>>5)*4 + (m>>4))*512 + ((((k>>3)&3)<<4) | (m&15))*8 + (k&7)
// so that wave-load "base + lane*16B" for (kstep, mtile) yields the MFMA
// A-operand fragment A[m=lane&15][k=quad*8+e] directly (m120-verified layout).
__device__ __forceinline__ size_t afrag_off(int m, int k) {
    return (size_t)(((k >> 5) * 4 + (m >> 4)) * 512 + (((((k >> 3) & 3) << 4) | (m & 15)) * 8) + (k & 7));
}

// ---------------------------------------------------------------------------
// Pack cat(W,U) [2048 x 4096] fp32 -> fp16 B-fragment-linear, z-cols reordered
// as col' = j*4 + g (j = hidden unit, g = gate i,f,c,o). Column-group cg owns
// j in [cg*4, cg*4+4) -> 16 cols -> one N-tile. Per (cg, kstep) a contiguous
// 2KB tile: lane l holds B[k=kstep*32+(l>>4)*8+e][n=l&15], n -> j=cg*4+(n>>2), g=n&3.
// grid (64 ksteps, 256 cg) x 64 threads.
// ---------------------------------------------------------------------------
__global__ __launch_bounds__(64) void k_pack(
    const float* __restrict__ W, const float* __restrict__ U, f16* __restrict__ out)
{
    const int kstep = blockIdx.x, cg = blockIdx.y, l = threadIdx.x;
    const int n = l & 15, q = l >> 4;
    const int stdcol = (n & 3) * HH + cg * 4 + (n >> 2);
    f16x8 v;
#pragma unroll
    for (int e = 0; e < 8; ++e) {
        int k = kstep * 32 + q * 8 + e;
        float s = (k < DIN) ? W[(size_t)k * G4 + stdcol] : U[(size_t)(k - DIN) * G4 + stdcol];
        v[e] = (f16)s;
    }
    *(f16x8*)(out + ((size_t)(cg * 64 + kstep) * 64 + l) * 8) = v;
}

// ---------------------------------------------------------------------------
// Kernel 1: XinF[t] = tanh(x[b][t][:] @ Wi + bi), written fp16 A-frag layout.
// ---------------------------------------------------------------------------
__global__ __launch_bounds__(256) void k_dense_in(
    const float* __restrict__ x, const float* __restrict__ Wi,
    const float* __restrict__ bi, f16* __restrict__ XinF)
{
    __shared__ float xs[16][FF];   // 32 KB
    const int jb  = blockIdx.x;    // 0..3
    const int rb  = blockIdx.y;    // 0..2047
    const int tid = threadIdx.x;

    const float4* xsrc = (const float4*)(x + (size_t)rb * 16 * FF);
    float4* xdst = (float4*)(&xs[0][0]);
#pragma unroll
    for (int i = 0; i < 8; ++i) xdst[tid + i * 256] = xsrc[tid + i * 256];
    __syncthreads();

    const int j = jb * 256 + tid;
    float acc[16];
#pragma unroll
    for (int r = 0; r < 16; ++r) acc[r] = 0.f;

    for (int k = 0; k < FF; ++k) {
        float w = Wi[(size_t)k * DIN + j];
#pragma unroll
        for (int r = 0; r < 16; ++r) acc[r] += xs[r][k] * w;
    }
    const float bbv = bi[j];
#pragma unroll
    for (int r = 0; r < 16; ++r) {
        int g = rb * 16 + r;
        int b = g >> 9;        // row in GEMM
        int t = g & 511;
        XinF[(size_t)t * (BB * DIN) + afrag_off(b, j)] = (f16)tanhf(acc[r] + bbv);
    }
}

// ---------------------------------------------------------------------------
// Kernel 2: one LSTM cell. z[64 x 4096] = [A1|A2] @ Bp + bias -> gates -> c,h.
// A1, A2: fp16 A-frag [64 x 1024] each (K 0..1023 and 1024..2047).
// Bp: packed fp16 weights. grid 256 blocks (= col-groups, 4 j each),
// 256 threads = 4 waves = 4-way K-split (512 K per wave, 16 ksteps).
// Each wave: 4 M-tiles x 1 N-tile, 64 MFMAs. LDS-reduce, fused gate epilogue.
// h written fp16 A-frag for the next GEMM; c fp32 linear in-place.
// ---------------------------------------------------------------------------
__global__ __launch_bounds__(256) void k_cell(
    const f16* __restrict__ A1, const f16* __restrict__ A2,
    const f16* __restrict__ Bp, const float* __restrict__ bias,
    float* __restrict__ c, f16* __restrict__ h_out)
{
    __shared__ float red[4][4][64][4];   // [ks][mtile][lane][reg] = 16 KB
    const int tid  = threadIdx.x;
    const int ks   = tid >> 6;
    const int lane = tid & 63;
    const int cg   = blockIdx.x;

    const f16* Ap = (ks < 2 ? A1 : A2) + ((size_t)((ks & 1) * 16) * 4 + 0) * 512 + (size_t)lane * 8;
    const f16* Bq = Bp + ((size_t)(cg * 64 + ks * 16) * 64 + lane) * 8;

    f32x4 acc[4] = {{0.f,0.f,0.f,0.f},{0.f,0.f,0.f,0.f},{0.f,0.f,0.f,0.f},{0.f,0.f,0.f,0.f}};
#pragma unroll 4
    for (int i = 0; i < 16; ++i) {
        f16x8 bfr = *(const f16x8*)(Bq + (size_t)i * 512);
#pragma unroll
        for (int m = 0; m < 4; ++m) {
            f16x8 afr = *(const f16x8*)(Ap + ((size_t)i * 4 + m) * 512);
            acc[m] = __builtin_amdgcn_mfma_f32_16x16x32_f16(afr, bfr, acc[m], 0, 0, 0);
        }
    }
#pragma unroll
    for (int m = 0; m < 4; ++m)
        *(f32x4*)&red[ks][m][lane][0] = acc[m];
    __syncthreads();

    // epilogue: thread -> (row, jq). C/D layout: col=lane&15, row=(lane>>4)*4+reg.
    const int row = tid & 63;
    const int jq  = tid >> 6;               // 0..3
    const int jg  = cg * 4 + jq;            // global hidden unit
    const int mt  = row >> 4, sub = row & 15;
    const int slq = (sub >> 2) << 4, reg = sub & 3;
    float z[4];
#pragma unroll
    for (int g = 0; g < 4; ++g) {
        const int sl = slq | (jq * 4 + g);
        z[g] = red[0][mt][sl][reg] + red[1][mt][sl][reg]
             + red[2][mt][sl][reg] + red[3][mt][sl][reg]
             + bias[g * HH + jg];
    }
    const float ig = 1.f / (1.f + expf(-z[0]));
    const float fg = 1.f / (1.f + expf(-z[1]));
    const float cc = tanhf(z[2]);
    const float og = 1.f / (1.f + expf(-z[3]));
    const int idx = row * HH + jg;
    const float cn = fg * c[idx] + ig * cc;
    c[idx] = cn;
    h_out[afrag_off(row, jg)] = (f16)(og * tanhf(cn));
}

// ---------------------------------------------------------------------------
// Kernel 3: out[b][o] = tanh(h1[b,:] @ Wo[:,o] + bo[o]); h1 in fp16 A-frag.
// ---------------------------------------------------------------------------
__global__ __launch_bounds__(128) void k_out(
    const f16* __restrict__ h1f, const float* __restrict__ Wo,
    const float* __restrict__ bo, float* __restrict__ out)
{
    __shared__ float hs[HH];
    const int b = blockIdx.x;
    for (int i = threadIdx.x; i < HH; i += 128) hs[i] = (float)h1f[afrag_off(b, i)];
    __syncthreads();
    const int o = threadIdx.x;
    float acc = 0.f;
    for (int k = 0; k < HH; ++k) acc += hs[k] * Wo[k * DOUT + o];
    out[b * DOUT + o] = tanhf(acc + bo[o]);
}

// ---------------------------------------------------------------------------
extern "C" void kernel_launch(void* const* d_in, const int* in_sizes, int n_in,
                              void* d_out, int out_size, void* d_ws, size_t ws_size,
                              hipStream_t stream)
{
    const float* x  = (const float*)d_in[0];
    const float* Wi = (const float*)d_in[1];
    const float* bi = (const float*)d_in[2];
    const float* W0 = (const float*)d_in[3];
    const float* U0 = (const float*)d_in[4];
    const float* b0 = (const float*)d_in[5];
    const float* W1 = (const float*)d_in[6];
    const float* U1 = (const float*)d_in[7];
    const float* b1 = (const float*)d_in[8];
    const float* Wo = (const float*)d_in[9];
    const float* bo = (const float*)d_in[10];
    float* out = (float*)d_out;

    f16* ws16 = (f16*)d_ws;
    const size_t ABUF = (size_t)BB * DIN;          // 65536 elements
    f16* XinF = ws16;                              // 512 * 65536 halves (64 MB... 67MB)
    f16* pW0  = XinF + (size_t)TT * ABUF;          // 2048*4096 halves
    f16* pW1  = pW0 + (size_t)2048 * G4;
    f16* h0a  = pW1 + (size_t)2048 * G4;
    f16* h0b  = h0a + ABUF;
    f16* h1a  = h0b + ABUF;
    f16* h1b  = h1a + ABUF;
    float* c0 = (float*)(h1b + ABUF);
    float* c1 = c0 + ABUF;

    // zero h (read at t=0) and c; region is contiguous: 4*128KB + 2*256KB
    hipMemsetAsync(h0a, 0, 4 * ABUF * sizeof(f16) + 2 * ABUF * sizeof(float), stream);

    k_pack<<<dim3(64, 256), 64, 0, stream>>>(W0, U0, pW0);
    k_pack<<<dim3(64, 256), 64, 0, stream>>>(W1, U1, pW1);
    k_dense_in<<<dim3(DIN / 256, (BB * TT) / 16), 256, 0, stream>>>(x, Wi, bi, XinF);

    const f16* h0r = h0a; f16* h0w = h0b;
    const f16* h1r = h1a; f16* h1w = h1b;
    for (int t = 0; t < TT; ++t) {
        k_cell<<<256, 256, 0, stream>>>(XinF + (size_t)t * ABUF, h0r, pW0, b0, c0, h0w);
        k_cell<<<256, 256, 0, stream>>>(h0w, h1r, pW1, b1, c1, h1w);
        const f16* tmp;
        tmp = h0r; h0r = h0w; h0w = (f16*)tmp;
        tmp = h1r; h1r = h1w; h1w = (f16*)tmp;
    }
    k_out<<<BB, 128, 0, stream>>>(h1r, Wo, bo, out);
}

// Round 3
// 7586.216 us; speedup vs baseline: 11.6990x; 1.4559x over previous
//
#include <hip/hip_runtime.h>
#include <math.h>

#define BB 64
#define TT 512
#define FF 512
#define DIN 1024
#define HH 1024
#define G4 4096
#define DOUT 128

typedef _Float16 f16;
typedef _Float16 f16x8 __attribute__((ext_vector_type(8)));
typedef float f32x4 __attribute__((ext_vector_type(4)));

// A-fragment-linear layout for a [64 x 1024] fp16 activation matrix:
//   element (m=row 0..63, k=col 0..1023) lives at
//   ((k>>5)*4 + (m>>4))*512 + ((((k>>3)&3)<<4) | (m&15))*8 + (k&7)
// so a wave-load "base + lane*16B" yields the MFMA A-fragment directly.
__device__ __forceinline__ size_t afrag_off(int m, int k) {
    return (size_t)(((k >> 5) * 4 + (m >> 4)) * 512 + (((((k >> 3) & 3) << 4) | (m & 15)) * 8) + (k & 7));
}

// ---------------------------------------------------------------------------
// Pack cat(W,U) [2048 x 4096] fp32 -> fp16 B-fragment-linear, z-cols reordered
// as col' = j*4 + g. Per (cg, kstep) a contiguous 1KB fragment tile.
// ---------------------------------------------------------------------------
__global__ __launch_bounds__(64) void k_pack(
    const float* __restrict__ W, const float* __restrict__ U, f16* __restrict__ out)
{
    const int kstep = blockIdx.x, cg = blockIdx.y, l = threadIdx.x;
    const int n = l & 15, q = l >> 4;
    const int stdcol = (n & 3) * HH + cg * 4 + (n >> 2);
    f16x8 v;
#pragma unroll
    for (int e = 0; e < 8; ++e) {
        int k = kstep * 32 + q * 8 + e;
        float s = (k < DIN) ? W[(size_t)k * G4 + stdcol] : U[(size_t)(k - DIN) * G4 + stdcol];
        v[e] = (f16)s;
    }
    *(f16x8*)(out + ((size_t)(cg * 64 + kstep) * 64 + l) * 8) = v;
}

// ---------------------------------------------------------------------------
// Kernel 1: XinF[t] = tanh(x[b][t][:] @ Wi + bi), written fp16 A-frag layout.
// ---------------------------------------------------------------------------
__global__ __launch_bounds__(256) void k_dense_in(
    const float* __restrict__ x, const float* __restrict__ Wi,
    const float* __restrict__ bi, f16* __restrict__ XinF)
{
    __shared__ float xs[16][FF];   // 32 KB
    const int jb  = blockIdx.x;
    const int rb  = blockIdx.y;
    const int tid = threadIdx.x;

    const float4* xsrc = (const float4*)(x + (size_t)rb * 16 * FF);
    float4* xdst = (float4*)(&xs[0][0]);
#pragma unroll
    for (int i = 0; i < 8; ++i) xdst[tid + i * 256] = xsrc[tid + i * 256];
    __syncthreads();

    const int j = jb * 256 + tid;
    float acc[16];
#pragma unroll
    for (int r = 0; r < 16; ++r) acc[r] = 0.f;

    for (int k = 0; k < FF; ++k) {
        float w = Wi[(size_t)k * DIN + j];
#pragma unroll
        for (int r = 0; r < 16; ++r) acc[r] += xs[r][k] * w;
    }
    const float bbv = bi[j];
#pragma unroll
    for (int r = 0; r < 16; ++r) {
        int g = rb * 16 + r;
        int b = g >> 9;
        int t = g & 511;
        XinF[(size_t)t * (BB * DIN) + afrag_off(b, j)] = (f16)tanhf(acc[r] + bbv);
    }
}

// ---------------------------------------------------------------------------
// Kernel 2: one pipeline PHASE = layer-0 cell @ t=p  +  layer-1 cell @ t=p-1.
// Grid 256 blocks: blocks [0,128) = layer 0, [128,256) = layer 1; each block
// owns 8 hidden units (2 N-tiles of packed cols). 512 threads = 8 waves,
// 8-way K-split (K=256/wave). Per wave: 8 ksteps x (4 M-tiles x 2 N-tiles)
// = 64 MFMAs. LDS-reduce over waves, fused gate epilogue.
// Double-buffered h by phase parity: reads (p-1)&1, writes p&1.
// ---------------------------------------------------------------------------
__global__ __launch_bounds__(512) void k_phase(
    const f16* __restrict__ XinF,
    f16* __restrict__ h0p0, f16* __restrict__ h0p1,
    f16* __restrict__ h1p0, f16* __restrict__ h1p1,
    const f16* __restrict__ pW0, const f16* __restrict__ pW1,
    const float* __restrict__ b0, const float* __restrict__ b1,
    float* __restrict__ c0, float* __restrict__ c1, int p)
{
    const int lay = blockIdx.x >> 7;
    const int cgb = blockIdx.x & 127;
    if (lay == 0 && p == TT) return;   // no L0 work in final phase
    if (lay == 1 && p == 0) return;    // no L1 work in first phase

    const int wp = p & 1, rp = (p + 1) & 1;
    const f16* h0r = rp ? h0p1 : h0p0;
    f16*       h0w = wp ? h0p1 : h0p0;
    const f16* h1r = rp ? h1p1 : h1p0;
    f16*       h1w = wp ? h1p1 : h1p0;

    const size_t ABUF = (size_t)BB * DIN;
    const f16* A1   = (lay == 0) ? XinF + (size_t)p * ABUF : h0r;
    const f16* A2   = (lay == 0) ? h0r : h1r;
    const f16* Bp   = (lay == 0) ? pW0 : pW1;
    const float* bias = (lay == 0) ? b0 : b1;
    float* c        = (lay == 0) ? c0 : c1;
    f16*   hw       = (lay == 0) ? h0w : h1w;

    __shared__ float red[8][4][2][64][4];   // [ks][mt][n][sl][reg] = 64 KB

    const int tid  = threadIdx.x;
    const int ks   = tid >> 6;     // 0..7 K-split (waves)
    const int lane = tid & 63;

    const f16* Ab = (ks < 4) ? A1 : A2;
    const int kloc0 = (ks & 3) * 8;                 // starting kstep in A-half
    const f16* Ap  = Ab + (size_t)(kloc0 * 4) * 512 + (size_t)lane * 8;
    const f16* Bq0 = Bp + ((size_t)((cgb * 2 + 0) * 64 + ks * 8) * 64 + lane) * 8;
    const f16* Bq1 = Bp + ((size_t)((cgb * 2 + 1) * 64 + ks * 8) * 64 + lane) * 8;

    f32x4 acc[4][2];
#pragma unroll
    for (int m = 0; m < 4; ++m)
#pragma unroll
        for (int n = 0; n < 2; ++n) acc[m][n] = (f32x4){0.f, 0.f, 0.f, 0.f};

#pragma unroll 2
    for (int i = 0; i < 8; ++i) {
        f16x8 bf0 = *(const f16x8*)(Bq0 + (size_t)i * 512);
        f16x8 bf1 = *(const f16x8*)(Bq1 + (size_t)i * 512);
#pragma unroll
        for (int m = 0; m < 4; ++m) {
            f16x8 af = *(const f16x8*)(Ap + ((size_t)i * 4 + m) * 512);
            acc[m][0] = __builtin_amdgcn_mfma_f32_16x16x32_f16(af, bf0, acc[m][0], 0, 0, 0);
            acc[m][1] = __builtin_amdgcn_mfma_f32_16x16x32_f16(af, bf1, acc[m][1], 0, 0, 0);
        }
    }

#pragma unroll
    for (int m = 0; m < 4; ++m)
#pragma unroll
        for (int n = 0; n < 2; ++n)
            *(f32x4*)&red[ks][m][n][lane][0] = acc[m][n];
    __syncthreads();

    // Epilogue: thread -> (row 0..63, jq 0..7). C/D: col=lane&15, row=(lane>>4)*4+reg.
    {
        const int row = tid & 63;
        const int jq  = tid >> 6;
        const int n   = jq >> 2, jqi = jq & 3;
        const int jg  = (cgb * 2 + n) * 4 + jqi;
        const int mt  = row >> 4, sub = row & 15;
        const int slq = (sub >> 2) << 4, reg = sub & 3;
        float z[4];
#pragma unroll
        for (int g = 0; g < 4; ++g) {
            const int sl = slq | (jqi * 4 + g);
            float s = 0.f;
#pragma unroll
            for (int kk = 0; kk < 8; ++kk) s += red[kk][mt][n][sl][reg];
            z[g] = s + bias[g * HH + jg];
        }
        const float ig = 1.f / (1.f + expf(-z[0]));
        const float fg = 1.f / (1.f + expf(-z[1]));
        const float cc = tanhf(z[2]);
        const float og = 1.f / (1.f + expf(-z[3]));
        const int idx = row * HH + jg;
        const float cn = fg * c[idx] + ig * cc;
        c[idx] = cn;
        hw[afrag_off(row, jg)] = (f16)(og * tanhf(cn));
    }
}

// ---------------------------------------------------------------------------
// Kernel 3: out[b][o] = tanh(h1[b,:] @ Wo[:,o] + bo[o]); h1 in fp16 A-frag.
// ---------------------------------------------------------------------------
__global__ __launch_bounds__(128) void k_out(
    const f16* __restrict__ h1f, const float* __restrict__ Wo,
    const float* __restrict__ bo, float* __restrict__ out)
{
    __shared__ float hs[HH];
    const int b = blockIdx.x;
    for (int i = threadIdx.x; i < HH; i += 128) hs[i] = (float)h1f[afrag_off(b, i)];
    __syncthreads();
    const int o = threadIdx.x;
    float acc = 0.f;
    for (int k = 0; k < HH; ++k) acc += hs[k] * Wo[k * DOUT + o];
    out[b * DOUT + o] = tanhf(acc + bo[o]);
}

// ---------------------------------------------------------------------------
extern "C" void kernel_launch(void* const* d_in, const int* in_sizes, int n_in,
                              void* d_out, int out_size, void* d_ws, size_t ws_size,
                              hipStream_t stream)
{
    const float* x  = (const float*)d_in[0];
    const float* Wi = (const float*)d_in[1];
    const float* bi = (const float*)d_in[2];
    const float* W0 = (const float*)d_in[3];
    const float* U0 = (const float*)d_in[4];
    const float* b0 = (const float*)d_in[5];
    const float* W1 = (const float*)d_in[6];
    const float* U1 = (const float*)d_in[7];
    const float* b1 = (const float*)d_in[8];
    const float* Wo = (const float*)d_in[9];
    const float* bo = (const float*)d_in[10];
    float* out = (float*)d_out;

    f16* ws16 = (f16*)d_ws;
    const size_t ABUF = (size_t)BB * DIN;
    f16* XinF = ws16;
    f16* pW0  = XinF + (size_t)TT * ABUF;
    f16* pW1  = pW0 + (size_t)2048 * G4;
    f16* h0a  = pW1 + (size_t)2048 * G4;
    f16* h0b  = h0a + ABUF;
    f16* h1a  = h0b + ABUF;
    f16* h1b  = h1a + ABUF;
    float* c0 = (float*)(h1b + ABUF);
    float* c1 = c0 + ABUF;

    // zero h (both parities; h1 parity-0 is read before ever written) and c
    hipMemsetAsync(h0a, 0, 4 * ABUF * sizeof(f16) + 2 * ABUF * sizeof(float), stream);

    k_pack<<<dim3(64, 256), 64, 0, stream>>>(W0, U0, pW0);
    k_pack<<<dim3(64, 256), 64, 0, stream>>>(W1, U1, pW1);
    k_dense_in<<<dim3(DIN / 256, (BB * TT) / 16), 256, 0, stream>>>(x, Wi, bi, XinF);

    for (int p = 0; p <= TT; ++p)
        k_phase<<<256, 512, 0, stream>>>(XinF, h0a, h0b, h1a, h1b,
                                         pW0, pW1, b0, b1, c0, c1, p);

    // phase TT (=512) writes parity 0 -> h1a holds h1[T-1]
    k_out<<<BB, 128, 0, stream>>>(h1a, Wo, bo, out);
}